// Round 6
// baseline (436.500 us; speedup 1.0000x reference)
//
#include <hip/hip_runtime.h>
#include <hip/hip_bf16.h>

#define B_    32
#define C_    256
#define H_    56
#define W_    56
#define HW_   3136
#define P_    58          // padded spatial (halo of 1)
#define G_    8
#define COUT_ 256
#define KTOT_ 2304        // 256 * 9

typedef float f32x4 __attribute__((ext_vector_type(4)));
typedef int   i32x4 __attribute__((ext_vector_type(4)));

// ---------------------------------------------------------------------------
// Kernel 1 (v2: partial reduction at full occupancy). 2048 blocks (8/CU) each
// reduce a 49KB contiguous 1/8-slab of one (b,g) group into float2 partials.
// Final 8-way reduction folded into act_kernel.
// ---------------------------------------------------------------------------
__global__ __launch_bounds__(256)
void gn_partial_kernel(const float* __restrict__ x, float2* __restrict__ partial) {
    int blk = blockIdx.x;                      // (b*8+g)*8 + sub
    const float4* base = (const float4*)(x + (size_t)blk * 12544);
    float s1 = 0.f, s2 = 0.f;
    for (int i = threadIdx.x; i < 3136; i += 256) {   // 12544 floats / 4
        float4 v = base[i];
        s1 += v.x + v.y + v.z + v.w;
        s2 += v.x * v.x + v.y * v.y + v.z * v.z + v.w * v.w;
    }
    #pragma unroll
    for (int off = 32; off; off >>= 1) {
        s1 += __shfl_down(s1, off, 64);
        s2 += __shfl_down(s2, off, 64);
    }
    __shared__ float ra[4], rb[4];
    int lane = threadIdx.x & 63, wv = threadIdx.x >> 6;
    if (!lane) { ra[wv] = s1; rb[wv] = s2; }
    __syncthreads();
    if (threadIdx.x == 0) {
        float2 p;
        p.x = ra[0] + ra[1] + ra[2] + ra[3];
        p.y = rb[0] + rb[1] + rb[2] + rb[3];
        partial[blk] = p;
    }
}

// ---------------------------------------------------------------------------
// Kernel 2 (v5): GN + ReLU^2 + PACT quant -> zero-padded NHWC int8 buffer.
// Coalesced global reads into XOR-swizzled LDS (jj ^ ((c>>2)&7), stride 16
// fl4); quant/register-transpose out of LDS. Computes mu/rs from the 8 gn
// partials per group. qs = round(q)-128, halo = -128 (epilogue +128*tsum).
// ---------------------------------------------------------------------------
__global__ __launch_bounds__(256)
void act_kernel(const float* __restrict__ x, const float* __restrict__ gamma,
                const float* __restrict__ beta, const float* __restrict__ a_ptr,
                const float2* __restrict__ partial, char* __restrict__ q) {
    int by = blockIdx.x;                 // b*58 + y
    int b = by / P_;
    int y = by - b * P_;
    char* qrow = q + (size_t)by * P_ * C_;
    const int PADV = 0x80808080;         // four -128 bytes
    if (y == 0 || y == P_ - 1) {
        int4 pv = {PADV, PADV, PADV, PADV};
        for (int i = threadIdx.x; i < (P_ * C_) / 16; i += 256)
            ((int4*)qrow)[i] = pv;
        return;
    }
    int t = threadIdx.x;
    // halo columns (pixel 0 and 57): 64 ints each
    if (t < 64)            ((int*)qrow)[t] = PADV;
    else if (t < 128)      ((int*)(qrow + (P_ - 1) * C_))[t - 64] = PADV;

    // ---- coalesced stage: x[b, 0..255, y-1, 0..55] -> swizzled LDS ---------
    __shared__ float4 xs[256 * 16];      // 64 KB, stride 16, XOR-swizzled
    const float* xb2 = x + (size_t)b * C_ * HW_ + (y - 1) * W_;
    #pragma unroll
    for (int k = 0; k < 14; ++k) {       // 3584 chunks / 256 threads
        int idx = t + k * 256;
        int c   = idx / 14;              // channel
        int jj  = idx - c * 14;          // float4 index within row
        int key = (c >> 2) & 7;
        xs[c * 16 + (jj ^ key)] = *(const float4*)(xb2 + (size_t)c * HW_ + jj * 4);
    }
    __syncthreads();

    float a_c = fmaxf(a_ptr[0], 0.f) + 1e-8f;
    float S   = 255.f / a_c;

    int c4 = t & 63;                     // channels 4*c4 .. 4*c4+3 (same group)
    int wb = t >> 6;                     // starting w-block
    int g  = c4 >> 3;                    // == (4*c4) >> 5
    const float2* pp = partial + ((size_t)b * G_ + g) * 8;
    float s1 = 0.f, s2 = 0.f;
    #pragma unroll
    for (int p = 0; p < 8; ++p) { s1 += pp[p].x; s2 += pp[p].y; }
    float mu = s1 / 100352.f;
    float var = s2 / 100352.f - mu * mu;
    float rs = rsqrtf(var + 1e-5f);

    float ga[4], be[4];
    #pragma unroll
    for (int i = 0; i < 4; ++i) { ga[i] = gamma[4 * c4 + i]; be[i] = beta[4 * c4 + i]; }

    int rkey = c4 & 7;                   // read-side XOR key
    for (int j = wb; j < 14; j += 4) {
        float4 v[4];
        #pragma unroll
        for (int i = 0; i < 4; ++i)
            v[i] = xs[(4 * c4 + i) * 16 + (j ^ rkey)];
        int qv[4][4];
        #pragma unroll
        for (int i = 0; i < 4; ++i) {
            float f[4] = {v[i].x, v[i].y, v[i].z, v[i].w};
            #pragma unroll
            for (int s = 0; s < 4; ++s) {
                float yv = (f[s] - mu) * rs * ga[i] + be[i];
                float r  = fmaxf(yv, 0.f);
                float h2 = fminf(r * r, a_c);
                qv[i][s] = (int)rintf(h2 * S) - 128;
            }
        }
        #pragma unroll
        for (int s = 0; s < 4; ++s) {
            int packed = (qv[0][s] & 255) | ((qv[1][s] & 255) << 8) |
                         ((qv[2][s] & 255) << 16) | (qv[3][s] << 24);
            *(int*)(qrow + (j * 4 + s + 1) * C_ + 4 * c4) = packed;
        }
    }
}

// ---------------------------------------------------------------------------
// Kernel 3: ternary weight prep. One block per oc. Writes wt[tap][oc][ic]
// as int8 {-1,0,+1}, alpha[oc], and tsum[oc] = sum_k t[oc,k].
// ---------------------------------------------------------------------------
__global__ __launch_bounds__(256)
void wq_kernel(const float* __restrict__ wfp, char* __restrict__ wt,
               float* __restrict__ alphas, float* __restrict__ tsum) {
    int oc = blockIdx.x;
    int t  = threadIdx.x;
    const float* wr = wfp + (size_t)oc * KTOT_;
    float wl[9];
    float s = 0.f;
    #pragma unroll
    for (int j = 0; j < 9; ++j) { wl[j] = wr[t + j * 256]; s += fabsf(wl[j]); }

    __shared__ float red[4];
    int lane = t & 63, wv = t >> 6;
    #pragma unroll
    for (int off = 32; off; off >>= 1) s += __shfl_down(s, off, 64);
    if (!lane) red[wv] = s;
    __syncthreads();
    float thr = 0.05f * ((red[0] + red[1] + red[2] + red[3]) / (float)KTOT_);
    __syncthreads();

    float sm = 0.f, cnt = 0.f, ts = 0.f;
    #pragma unroll
    for (int j = 0; j < 9; ++j) {
        float aw = fabsf(wl[j]);
        if (aw > thr) {
            sm += aw; cnt += 1.f;
            ts += (wl[j] > 0.f) ? 1.f : -1.f;
        }
    }
    #pragma unroll
    for (int off = 32; off; off >>= 1) {
        sm  += __shfl_down(sm, off, 64);
        cnt += __shfl_down(cnt, off, 64);
        ts  += __shfl_down(ts, off, 64);
    }
    __shared__ float redc[4], redt[4];
    if (!lane) { red[wv] = sm; redc[wv] = cnt; redt[wv] = ts; }
    __syncthreads();
    if (t == 0) {
        float alpha = (red[0] + red[1] + red[2] + red[3]) /
                      (redc[0] + redc[1] + redc[2] + redc[3] + 1e-8f);
        alphas[oc] = alpha;
        tsum[oc] = redt[0] + redt[1] + redt[2] + redt[3];
    }
    #pragma unroll
    for (int j = 0; j < 9; ++j) {
        int i  = t + j * 256;           // i = ic*9 + tap
        int ic = i / 9;
        int tap = i - ic * 9;
        float w = wl[j];
        char tern = (fabsf(w) > thr) ? (w > 0.f ? (char)1 : (char)-1) : (char)0;
        wt[((size_t)tap * 256 + oc) * 256 + ic] = tern;
    }
}

// ---------------------------------------------------------------------------
// Kernel 4 (v6: LDS-free, barrier-free, all-from-L2): implicit-GEMM conv,
// i8 MFMA. Rationale (r5 post-mortem): every explicit pipeline at 1 blk/CU
// lost to 2-blk TLP; the 64V+64A budget has zero headroom. But both operands
// are already L2-resident (wt = 576KB; qbuf per-XCD slice ~3.2MB, proven by
// FETCH ~= 1 cold pass), and MFMA fragments are 16 contiguous bytes in both
// NHWC qbuf and wt[tap][oc][ic] -- directly loadable per-lane. So: NO LDS,
// NO barriers, NO DMA. Pure global_load_dwordx4 -> MFMA stream, K-loop fully
// unrolled, compiler schedules/hoists freely (no vmcnt(0) drains anywhere).
// 256-thr blocks (dodges the 512-thr occupancy cliff), 128x128 tile, 2x2
// waves of 64x64, grid 1568 = 8*196 XCD-chunked (nhalf pairs sharing A on
// one XCD). A-frag lines shared by 4 quads (16 lines/wave-load); twin waves
// (wn-pair on A, wm-pair on B) dedupe in L1. ~24 B/cyc/CU from L2 << ceiling.
// Exact integer arithmetic; epilogue adds 128*tsum[oc] shift correction.
// ---------------------------------------------------------------------------
__global__ __launch_bounds__(256, 3)
void conv_gemm_kernel(const char* __restrict__ q, const char* __restrict__ wt,
                      const float* __restrict__ alphas, const float* __restrict__ bias,
                      const float* __restrict__ tsum, const float* __restrict__ a_ptr,
                      float* __restrict__ out) {
    int bid = blockIdx.x;                     // 1568 = 8 * 196
    int virt = (bid & 7) * 196 + (bid >> 3);  // XCD-chunked bijective swizzle
    int mt = virt >> 1;                       // 784 M-tiles of 128
    int nh = virt & 1;                        // N-half (oc base = nh*128)
    int tid = threadIdx.x;                    // 0..255
    int lane = tid & 63;
    int wv = tid >> 6;                        // 0..3
    int wm = wv & 1, wn = wv >> 1;            // 2x2 waves of 64x64
    int quad = lane >> 4, lrow = lane & 15;

    // per-lane A fragment offsets: 4 owned m-rows -> qbuf pixel base + quad*16
    int aoff[4];
    #pragma unroll
    for (int mi = 0; mi < 4; ++mi) {
        int m = mt * 128 + wm * 64 + lrow + mi * 16;
        int b = m / HW_;
        int rem = m - b * HW_;
        int hh = rem / W_;
        int ww = rem - hh * W_;
        aoff[mi] = ((b * P_ + hh + 1) * P_ + (ww + 1)) * C_ + quad * 16;
    }
    // per-lane B fragment offsets: 4 owned oc-rows in wt[tap][oc][ic]
    int boff[4];
    #pragma unroll
    for (int ni = 0; ni < 4; ++ni)
        boff[ni] = (nh * 128 + wn * 64 + ni * 16 + lrow) * 256 + quad * 16;

    i32x4 acc[4][4];
    #pragma unroll
    for (int i = 0; i < 4; ++i)
        #pragma unroll
        for (int j = 0; j < 4; ++j) { acc[i][j][0]=0; acc[i][j][1]=0; acc[i][j][2]=0; acc[i][j][3]=0; }

    #pragma unroll
    for (int kk = 0; kk < 18; ++kk) {
        const int tap = kk >> 1;                  // compile-time constants:
        const int ic0 = (kk & 1) << 7;            // whole loop fully unrolled
        const int dh  = tap / 3 - 1;
        const int dw  = tap - (tap / 3) * 3 - 1;
        const char* qk = q  + ((dh * P_ + dw) * C_ + ic0);   // >= q (halo pad)
        const char* wk = wt + tap * 65536 + ic0;
        #pragma unroll
        for (int ks = 0; ks < 2; ++ks) {
            i32x4 af[4], bf[4];
            #pragma unroll
            for (int mi = 0; mi < 4; ++mi)
                af[mi] = *(const i32x4*)(qk + aoff[mi] + ks * 64);
            #pragma unroll
            for (int ni = 0; ni < 4; ++ni)
                bf[ni] = *(const i32x4*)(wk + boff[ni] + ks * 64);
            #pragma unroll
            for (int mi = 0; mi < 4; ++mi)
                #pragma unroll
                for (int ni = 0; ni < 4; ++ni)
                    acc[mi][ni] = __builtin_amdgcn_mfma_i32_16x16x64_i8(
                        af[mi], bf[ni], acc[mi][ni], 0, 0, 0);
        }
    }

    float a_c = fmaxf(a_ptr[0], 0.f) + 1e-8f;
    float qs  = a_c * (1.f / 255.f);
    #pragma unroll
    for (int ni = 0; ni < 4; ++ni) {
        int n = nh * 128 + wn * 64 + ni * 16 + lrow;
        float sc = alphas[n] * qs;
        float bn = bias[n];
        float corr = 128.f * tsum[n];       // undo the -128 activation shift
        #pragma unroll
        for (int mi = 0; mi < 4; ++mi) {
            int mbase = mt * 128 + wm * 64 + mi * 16 + quad * 4;
            int b = mbase / HW_;
            size_t off = (size_t)b * (C_ * HW_) + (size_t)n * HW_ + (mbase - b * HW_);
            f32x4 v;
            #pragma unroll
            for (int r = 0; r < 4; ++r)
                v[r] = ((float)acc[mi][ni][r] + corr) * sc + bn;
            *(f32x4*)(out + off) = v;
        }
    }
}

// ---------------------------------------------------------------------------
extern "C" void kernel_launch(void* const* d_in, const int* in_sizes, int n_in,
                              void* d_out, int out_size, void* d_ws, size_t ws_size,
                              hipStream_t stream) {
    const float* x     = (const float*)d_in[0];
    const float* gamma = (const float*)d_in[1];
    const float* beta  = (const float*)d_in[2];
    const float* a     = (const float*)d_in[3];
    const float* wfp   = (const float*)d_in[4];
    const float* bias  = (const float*)d_in[5];
    float* out = (float*)d_out;

    char* ws = (char*)d_ws;
    char*   qbuf    = ws;                                      // 32*58*58*256 i8 = 27,557,888 B
    char*   wtb     = ws + 27557888;                           // 9*256*256 i8  = 589,824 B
    float*  alphas  = (float*)(ws + 27557888 + 589824);        // 256 fp32
    float*  tsum    = alphas + 256;                            // 256 fp32
    float2* partial = (float2*)(tsum + 256);                   // 2048 float2 = 16 KB

    gn_partial_kernel<<<2048, 256, 0, stream>>>(x, partial);
    wq_kernel<<<COUT_, 256, 0, stream>>>(wfp, wtb, alphas, tsum);
    act_kernel<<<B_ * P_, 256, 0, stream>>>(x, gamma, beta, a, partial, qbuf);
    conv_gemm_kernel<<<1568, 256, 0, stream>>>(qbuf, wtb, alphas, bias, tsum, a, out);
}

// Round 7
// 275.627 us; speedup vs baseline: 1.5837x; 1.5837x over previous
//
#include <hip/hip_runtime.h>
#include <hip/hip_bf16.h>

#define B_    32
#define C_    256
#define H_    56
#define W_    56
#define HW_   3136
#define P_    58          // padded spatial (halo of 1)
#define G_    8
#define COUT_ 256
#define KTOT_ 2304        // 256 * 9

typedef float f32x4 __attribute__((ext_vector_type(4)));
typedef int   i32x4 __attribute__((ext_vector_type(4)));

// ---------------------------------------------------------------------------
// Kernel 1 (v2: partial reduction at full occupancy). 2048 blocks (8/CU) each
// reduce a 49KB contiguous 1/8-slab of one (b,g) group into float2 partials.
// Final 8-way reduction folded into act_kernel.
// ---------------------------------------------------------------------------
__global__ __launch_bounds__(256)
void gn_partial_kernel(const float* __restrict__ x, float2* __restrict__ partial) {
    int blk = blockIdx.x;                      // (b*8+g)*8 + sub
    const float4* base = (const float4*)(x + (size_t)blk * 12544);
    float s1 = 0.f, s2 = 0.f;
    for (int i = threadIdx.x; i < 3136; i += 256) {   // 12544 floats / 4
        float4 v = base[i];
        s1 += v.x + v.y + v.z + v.w;
        s2 += v.x * v.x + v.y * v.y + v.z * v.z + v.w * v.w;
    }
    #pragma unroll
    for (int off = 32; off; off >>= 1) {
        s1 += __shfl_down(s1, off, 64);
        s2 += __shfl_down(s2, off, 64);
    }
    __shared__ float ra[4], rb[4];
    int lane = threadIdx.x & 63, wv = threadIdx.x >> 6;
    if (!lane) { ra[wv] = s1; rb[wv] = s2; }
    __syncthreads();
    if (threadIdx.x == 0) {
        float2 p;
        p.x = ra[0] + ra[1] + ra[2] + ra[3];
        p.y = rb[0] + rb[1] + rb[2] + rb[3];
        partial[blk] = p;
    }
}

// ---------------------------------------------------------------------------
// Kernel 2 (v5): GN + ReLU^2 + PACT quant -> zero-padded NHWC int8 buffer.
// Coalesced global reads into XOR-swizzled LDS (jj ^ ((c>>2)&7), stride 16
// fl4); quant/register-transpose out of LDS. Computes mu/rs from the 8 gn
// partials per group. qs = round(q)-128, halo = -128 (epilogue +128*tsum).
// ---------------------------------------------------------------------------
__global__ __launch_bounds__(256)
void act_kernel(const float* __restrict__ x, const float* __restrict__ gamma,
                const float* __restrict__ beta, const float* __restrict__ a_ptr,
                const float2* __restrict__ partial, char* __restrict__ q) {
    int by = blockIdx.x;                 // b*58 + y
    int b = by / P_;
    int y = by - b * P_;
    char* qrow = q + (size_t)by * P_ * C_;
    const int PADV = 0x80808080;         // four -128 bytes
    if (y == 0 || y == P_ - 1) {
        int4 pv = {PADV, PADV, PADV, PADV};
        for (int i = threadIdx.x; i < (P_ * C_) / 16; i += 256)
            ((int4*)qrow)[i] = pv;
        return;
    }
    int t = threadIdx.x;
    // halo columns (pixel 0 and 57): 64 ints each
    if (t < 64)            ((int*)qrow)[t] = PADV;
    else if (t < 128)      ((int*)(qrow + (P_ - 1) * C_))[t - 64] = PADV;

    // ---- coalesced stage: x[b, 0..255, y-1, 0..55] -> swizzled LDS ---------
    __shared__ float4 xs[256 * 16];      // 64 KB, stride 16, XOR-swizzled
    const float* xb2 = x + (size_t)b * C_ * HW_ + (y - 1) * W_;
    #pragma unroll
    for (int k = 0; k < 14; ++k) {       // 3584 chunks / 256 threads
        int idx = t + k * 256;
        int c   = idx / 14;              // channel
        int jj  = idx - c * 14;          // float4 index within row
        int key = (c >> 2) & 7;
        xs[c * 16 + (jj ^ key)] = *(const float4*)(xb2 + (size_t)c * HW_ + jj * 4);
    }
    __syncthreads();

    float a_c = fmaxf(a_ptr[0], 0.f) + 1e-8f;
    float S   = 255.f / a_c;

    int c4 = t & 63;                     // channels 4*c4 .. 4*c4+3 (same group)
    int wb = t >> 6;                     // starting w-block
    int g  = c4 >> 3;                    // == (4*c4) >> 5
    const float2* pp = partial + ((size_t)b * G_ + g) * 8;
    float s1 = 0.f, s2 = 0.f;
    #pragma unroll
    for (int p = 0; p < 8; ++p) { s1 += pp[p].x; s2 += pp[p].y; }
    float mu = s1 / 100352.f;
    float var = s2 / 100352.f - mu * mu;
    float rs = rsqrtf(var + 1e-5f);

    float ga[4], be[4];
    #pragma unroll
    for (int i = 0; i < 4; ++i) { ga[i] = gamma[4 * c4 + i]; be[i] = beta[4 * c4 + i]; }

    int rkey = c4 & 7;                   // read-side XOR key
    for (int j = wb; j < 14; j += 4) {
        float4 v[4];
        #pragma unroll
        for (int i = 0; i < 4; ++i)
            v[i] = xs[(4 * c4 + i) * 16 + (j ^ rkey)];
        int qv[4][4];
        #pragma unroll
        for (int i = 0; i < 4; ++i) {
            float f[4] = {v[i].x, v[i].y, v[i].z, v[i].w};
            #pragma unroll
            for (int s = 0; s < 4; ++s) {
                float yv = (f[s] - mu) * rs * ga[i] + be[i];
                float r  = fmaxf(yv, 0.f);
                float h2 = fminf(r * r, a_c);
                qv[i][s] = (int)rintf(h2 * S) - 128;
            }
        }
        #pragma unroll
        for (int s = 0; s < 4; ++s) {
            int packed = (qv[0][s] & 255) | ((qv[1][s] & 255) << 8) |
                         ((qv[2][s] & 255) << 16) | (qv[3][s] << 24);
            *(int*)(qrow + (j * 4 + s + 1) * C_ + 4 * c4) = packed;
        }
    }
}

// ---------------------------------------------------------------------------
// Kernel 3: ternary weight prep. One block per oc. Writes wt[tap][oc][ic]
// as int8 {-1,0,+1}, alpha[oc], and tsum[oc] = sum_k t[oc,k].
// ---------------------------------------------------------------------------
__global__ __launch_bounds__(256)
void wq_kernel(const float* __restrict__ wfp, char* __restrict__ wt,
               float* __restrict__ alphas, float* __restrict__ tsum) {
    int oc = blockIdx.x;
    int t  = threadIdx.x;
    const float* wr = wfp + (size_t)oc * KTOT_;
    float wl[9];
    float s = 0.f;
    #pragma unroll
    for (int j = 0; j < 9; ++j) { wl[j] = wr[t + j * 256]; s += fabsf(wl[j]); }

    __shared__ float red[4];
    int lane = t & 63, wv = t >> 6;
    #pragma unroll
    for (int off = 32; off; off >>= 1) s += __shfl_down(s, off, 64);
    if (!lane) red[wv] = s;
    __syncthreads();
    float thr = 0.05f * ((red[0] + red[1] + red[2] + red[3]) / (float)KTOT_);
    __syncthreads();

    float sm = 0.f, cnt = 0.f, ts = 0.f;
    #pragma unroll
    for (int j = 0; j < 9; ++j) {
        float aw = fabsf(wl[j]);
        if (aw > thr) {
            sm += aw; cnt += 1.f;
            ts += (wl[j] > 0.f) ? 1.f : -1.f;
        }
    }
    #pragma unroll
    for (int off = 32; off; off >>= 1) {
        sm  += __shfl_down(sm, off, 64);
        cnt += __shfl_down(cnt, off, 64);
        ts  += __shfl_down(ts, off, 64);
    }
    __shared__ float redc[4], redt[4];
    if (!lane) { red[wv] = sm; redc[wv] = cnt; redt[wv] = ts; }
    __syncthreads();
    if (t == 0) {
        float alpha = (red[0] + red[1] + red[2] + red[3]) /
                      (redc[0] + redc[1] + redc[2] + redc[3] + 1e-8f);
        alphas[oc] = alpha;
        tsum[oc] = redt[0] + redt[1] + redt[2] + redt[3];
    }
    #pragma unroll
    for (int j = 0; j < 9; ++j) {
        int i  = t + j * 256;           // i = ic*9 + tap
        int ic = i / 9;
        int tap = i - ic * 9;
        float w = wl[j];
        char tern = (fabsf(w) > thr) ? (w > 0.f ? (char)1 : (char)-1) : (char)0;
        wt[((size_t)tap * 256 + oc) * 256 + ic] = tern;
    }
}

// ---------------------------------------------------------------------------
// Kernel 4 (v7: r0 LDS body, 4 independent barrier domains per CU):
// implicit-GEMM conv, i8 MFMA. Scorecard so far: simple LDS + 2 blk/CU = 80us;
// all explicit pipelines (4-phase, dbuf, 3-buf counted-vmcnt) = 97-127us;
// LDS-free all-from-L2 = 241us (latency-bound: MfmaUtil 9.8%). Conclusion:
// keep the proven body (global_load_lds stage -> sync -> ds_read+MFMA ->
// sync), attack the per-tile vmcnt(0) drain with MORE independent blocks.
// 256 thr / 128x128 tile: LDS 32KB/block, ~64V+64A regs/wave (=128 unified
// -> 4 waves/SIMD) -> FOUR blocks/CU (128KB LDS, 16 waves), four staggered
// barrier domains: one block drains while three compute. Per-CU-tile math:
// staging 4x32KB ~ 2340 cyc L2-BW < MFMA 2616 cyc -> compute-dominant.
// Grid 1568 = 8*196 XCD-chunked; the two N-halves of each M-tile are
// adjacent -> same XCD -> A-tile L2 reuse (B = wt is 576KB, L2-resident).
// Exact integer arithmetic; epilogue adds 128*tsum[oc] shift correction.
// ---------------------------------------------------------------------------
__global__ __launch_bounds__(256, 4)
void conv_gemm_kernel(const char* __restrict__ q, const char* __restrict__ wt,
                      const float* __restrict__ alphas, const float* __restrict__ bias,
                      const float* __restrict__ tsum, const float* __restrict__ a_ptr,
                      float* __restrict__ out) {
    int bid = blockIdx.x;                     // 1568 = 8 * 196
    int virt = (bid & 7) * 196 + (bid >> 3);  // XCD-chunked bijective swizzle
    int mt = virt >> 1;                       // 784 M-tiles of 128
    int nh = virt & 1;                        // N-half (oc base = nh*128)
    int tid = threadIdx.x;                    // 0..255
    int lane = tid & 63;
    int wv = tid >> 6;                        // 0..3
    int wm = wv & 1, wn = wv >> 1;            // 2x2 waves of 64x64
    int quad = lane >> 4, lrow = lane & 15;

    __shared__ char As[128 * 128];   // 16 KB
    __shared__ char Bs[128 * 128];   // 16 KB

    // XOR bank swizzle on 16B K-blocks: slot kb holds global kb ^ (row&7)
    int kswz = (((tid & 7) ^ ((tid >> 3) & 7)) << 4);
    int sb[4], wb[4];
    #pragma unroll
    for (int r = 0; r < 4; ++r) {            // A rows: r*32 + (tid>>3)
        int ml = r * 32 + (tid >> 3);
        int m = mt * 128 + ml;
        int b = m / HW_;
        int rem = m - b * HW_;
        int hh = rem / W_;
        int ww = rem - hh * W_;
        sb[r] = ((b * P_ + hh + 1) * P_ + (ww + 1)) * C_ + kswz;
    }
    #pragma unroll
    for (int r = 0; r < 4; ++r) {            // B rows: local oc r*32 + (tid>>3)
        int oc = nh * 128 + r * 32 + (tid >> 3);
        wb[r] = oc * C_ + kswz;
    }

    i32x4 acc[4][4];
    #pragma unroll
    for (int i = 0; i < 4; ++i)
        #pragma unroll
        for (int j = 0; j < 4; ++j) { acc[i][j][0]=0; acc[i][j][1]=0; acc[i][j][2]=0; acc[i][j][3]=0; }

    int arow = wm * 64 + lrow;
    int brow = wn * 64 + lrow;
    int rsw = lrow & 7;          // read-side XOR key

    for (int kk = 0; kk < 18; ++kk) {
        int tap = kk >> 1;
        int ic0 = (kk & 1) << 7;
        int dh = tap / 3 - 1;
        int dw = tap - (tap / 3) * 3 - 1;
        int aoff = (dh * P_ + dw) * C_ + ic0;
        const char* gb = wt + (size_t)tap * (256 * 256) + ic0;
        #pragma unroll
        for (int r = 0; r < 4; ++r) {
            __builtin_amdgcn_global_load_lds(
                (const __attribute__((address_space(1))) void*)(q + sb[r] + aoff),
                (__attribute__((address_space(3))) void*)(&As[r * 4096 + tid * 16]),
                16, 0, 0);
        }
        #pragma unroll
        for (int r = 0; r < 4; ++r) {
            __builtin_amdgcn_global_load_lds(
                (const __attribute__((address_space(1))) void*)(gb + wb[r]),
                (__attribute__((address_space(3))) void*)(&Bs[r * 4096 + tid * 16]),
                16, 0, 0);
        }
        __syncthreads();
        #pragma unroll
        for (int ks = 0; ks < 2; ++ks) {
            int cb = (ks * 4 + quad) ^ rsw;
            i32x4 af[4], bf[4];
            #pragma unroll
            for (int mi = 0; mi < 4; ++mi)
                af[mi] = *(const i32x4*)&As[(arow + mi * 16) * 128 + cb * 16];
            #pragma unroll
            for (int ni = 0; ni < 4; ++ni)
                bf[ni] = *(const i32x4*)&Bs[(brow + ni * 16) * 128 + cb * 16];
            #pragma unroll
            for (int mi = 0; mi < 4; ++mi)
                #pragma unroll
                for (int ni = 0; ni < 4; ++ni)
                    acc[mi][ni] = __builtin_amdgcn_mfma_i32_16x16x64_i8(
                        af[mi], bf[ni], acc[mi][ni], 0, 0, 0);
        }
        __syncthreads();
    }

    float a_c = fmaxf(a_ptr[0], 0.f) + 1e-8f;
    float qs  = a_c * (1.f / 255.f);
    #pragma unroll
    for (int ni = 0; ni < 4; ++ni) {
        int n = nh * 128 + wn * 64 + ni * 16 + lrow;
        float sc = alphas[n] * qs;
        float bn = bias[n];
        float corr = 128.f * tsum[n];       // undo the -128 activation shift
        #pragma unroll
        for (int mi = 0; mi < 4; ++mi) {
            int mbase = mt * 128 + wm * 64 + mi * 16 + quad * 4;
            int b = mbase / HW_;
            size_t off = (size_t)b * (C_ * HW_) + (size_t)n * HW_ + (mbase - b * HW_);
            f32x4 v;
            #pragma unroll
            for (int r = 0; r < 4; ++r)
                v[r] = ((float)acc[mi][ni][r] + corr) * sc + bn;
            *(f32x4*)(out + off) = v;
        }
    }
}

// ---------------------------------------------------------------------------
extern "C" void kernel_launch(void* const* d_in, const int* in_sizes, int n_in,
                              void* d_out, int out_size, void* d_ws, size_t ws_size,
                              hipStream_t stream) {
    const float* x     = (const float*)d_in[0];
    const float* gamma = (const float*)d_in[1];
    const float* beta  = (const float*)d_in[2];
    const float* a     = (const float*)d_in[3];
    const float* wfp   = (const float*)d_in[4];
    const float* bias  = (const float*)d_in[5];
    float* out = (float*)d_out;

    char* ws = (char*)d_ws;
    char*   qbuf    = ws;                                      // 32*58*58*256 i8 = 27,557,888 B
    char*   wtb     = ws + 27557888;                           // 9*256*256 i8  = 589,824 B
    float*  alphas  = (float*)(ws + 27557888 + 589824);        // 256 fp32
    float*  tsum    = alphas + 256;                            // 256 fp32
    float2* partial = (float2*)(tsum + 256);                   // 2048 float2 = 16 KB

    gn_partial_kernel<<<2048, 256, 0, stream>>>(x, partial);
    wq_kernel<<<COUT_, 256, 0, stream>>>(wfp, wtb, alphas, tsum);
    act_kernel<<<B_ * P_, 256, 0, stream>>>(x, gamma, beta, a, partial, qbuf);
    conv_gemm_kernel<<<1568, 256, 0, stream>>>(qbuf, wtb, alphas, bias, tsum, a, out);
}

// Round 8
// 269.294 us; speedup vs baseline: 1.6209x; 1.0235x over previous
//
#include <hip/hip_runtime.h>
#include <hip/hip_bf16.h>

#define B_    32
#define C_    256
#define H_    56
#define W_    56
#define HW_   3136
#define P_    58          // padded spatial (halo of 1)
#define G_    8
#define COUT_ 256
#define KTOT_ 2304        // 256 * 9

typedef float f32x4 __attribute__((ext_vector_type(4)));
typedef int   i32x4 __attribute__((ext_vector_type(4)));

// ---------------------------------------------------------------------------
// Kernel 1 (fused prep): blocks [0,2048) = GN partial reduction (8 blocks/CU,
// 49KB contiguous slab -> float2 partial); blocks [2048,2304) = ternary
// weight prep (one block per oc). Fusion saves one launch + graph gap;
// per-block branch is uniform (no divergence). Bodies unchanged from r7.
// ---------------------------------------------------------------------------
__global__ __launch_bounds__(256)
void prep_kernel(const float* __restrict__ x, const float* __restrict__ wfp,
                 float2* __restrict__ partial, char* __restrict__ wt,
                 float* __restrict__ alphas, float* __restrict__ tsum) {
    if (blockIdx.x < 2048) {
        // ---- GN partial reduction ----
        int blk = blockIdx.x;                      // (b*8+g)*8 + sub
        const float4* base = (const float4*)(x + (size_t)blk * 12544);
        float s1 = 0.f, s2 = 0.f;
        for (int i = threadIdx.x; i < 3136; i += 256) {   // 12544 floats / 4
            float4 v = base[i];
            s1 += v.x + v.y + v.z + v.w;
            s2 += v.x * v.x + v.y * v.y + v.z * v.z + v.w * v.w;
        }
        #pragma unroll
        for (int off = 32; off; off >>= 1) {
            s1 += __shfl_down(s1, off, 64);
            s2 += __shfl_down(s2, off, 64);
        }
        __shared__ float ra[4], rb[4];
        int lane = threadIdx.x & 63, wv = threadIdx.x >> 6;
        if (!lane) { ra[wv] = s1; rb[wv] = s2; }
        __syncthreads();
        if (threadIdx.x == 0) {
            float2 p;
            p.x = ra[0] + ra[1] + ra[2] + ra[3];
            p.y = rb[0] + rb[1] + rb[2] + rb[3];
            partial[blk] = p;
        }
        return;
    }
    // ---- ternary weight prep ----
    int oc = blockIdx.x - 2048;
    int t  = threadIdx.x;
    const float* wr = wfp + (size_t)oc * KTOT_;
    float wl[9];
    float s = 0.f;
    #pragma unroll
    for (int j = 0; j < 9; ++j) { wl[j] = wr[t + j * 256]; s += fabsf(wl[j]); }

    __shared__ float red[4];
    int lane = t & 63, wv = t >> 6;
    #pragma unroll
    for (int off = 32; off; off >>= 1) s += __shfl_down(s, off, 64);
    if (!lane) red[wv] = s;
    __syncthreads();
    float thr = 0.05f * ((red[0] + red[1] + red[2] + red[3]) / (float)KTOT_);
    __syncthreads();

    float sm = 0.f, cnt = 0.f, ts = 0.f;
    #pragma unroll
    for (int j = 0; j < 9; ++j) {
        float aw = fabsf(wl[j]);
        if (aw > thr) {
            sm += aw; cnt += 1.f;
            ts += (wl[j] > 0.f) ? 1.f : -1.f;
        }
    }
    #pragma unroll
    for (int off = 32; off; off >>= 1) {
        sm  += __shfl_down(sm, off, 64);
        cnt += __shfl_down(cnt, off, 64);
        ts  += __shfl_down(ts, off, 64);
    }
    __shared__ float redc[4], redt[4];
    if (!lane) { red[wv] = sm; redc[wv] = cnt; redt[wv] = ts; }
    __syncthreads();
    if (t == 0) {
        float alpha = (red[0] + red[1] + red[2] + red[3]) /
                      (redc[0] + redc[1] + redc[2] + redc[3] + 1e-8f);
        alphas[oc] = alpha;
        tsum[oc] = redt[0] + redt[1] + redt[2] + redt[3];
    }
    #pragma unroll
    for (int j = 0; j < 9; ++j) {
        int i  = t + j * 256;           // i = ic*9 + tap
        int ic = i / 9;
        int tap = i - ic * 9;
        float w = wl[j];
        char tern = (fabsf(w) > thr) ? (w > 0.f ? (char)1 : (char)-1) : (char)0;
        wt[((size_t)tap * 256 + oc) * 256 + ic] = tern;
    }
}

// ---------------------------------------------------------------------------
// Kernel 2 (v5, unchanged): GN + ReLU^2 + PACT quant -> zero-padded NHWC int8.
// Coalesced global reads into XOR-swizzled LDS; quant/register-transpose out
// of LDS; mu/rs finalized from the 8 gn partials per group.
// ---------------------------------------------------------------------------
__global__ __launch_bounds__(256)
void act_kernel(const float* __restrict__ x, const float* __restrict__ gamma,
                const float* __restrict__ beta, const float* __restrict__ a_ptr,
                const float2* __restrict__ partial, char* __restrict__ q) {
    int by = blockIdx.x;                 // b*58 + y
    int b = by / P_;
    int y = by - b * P_;
    char* qrow = q + (size_t)by * P_ * C_;
    const int PADV = 0x80808080;         // four -128 bytes
    if (y == 0 || y == P_ - 1) {
        int4 pv = {PADV, PADV, PADV, PADV};
        for (int i = threadIdx.x; i < (P_ * C_) / 16; i += 256)
            ((int4*)qrow)[i] = pv;
        return;
    }
    int t = threadIdx.x;
    // halo columns (pixel 0 and 57): 64 ints each
    if (t < 64)            ((int*)qrow)[t] = PADV;
    else if (t < 128)      ((int*)(qrow + (P_ - 1) * C_))[t - 64] = PADV;

    // ---- coalesced stage: x[b, 0..255, y-1, 0..55] -> swizzled LDS ---------
    __shared__ float4 xs[256 * 16];      // 64 KB, stride 16, XOR-swizzled
    const float* xb2 = x + (size_t)b * C_ * HW_ + (y - 1) * W_;
    #pragma unroll
    for (int k = 0; k < 14; ++k) {       // 3584 chunks / 256 threads
        int idx = t + k * 256;
        int c   = idx / 14;              // channel
        int jj  = idx - c * 14;          // float4 index within row
        int key = (c >> 2) & 7;
        xs[c * 16 + (jj ^ key)] = *(const float4*)(xb2 + (size_t)c * HW_ + jj * 4);
    }
    __syncthreads();

    float a_c = fmaxf(a_ptr[0], 0.f) + 1e-8f;
    float S   = 255.f / a_c;

    int c4 = t & 63;                     // channels 4*c4 .. 4*c4+3 (same group)
    int wb = t >> 6;                     // starting w-block
    int g  = c4 >> 3;                    // == (4*c4) >> 5
    const float2* pp = partial + ((size_t)b * G_ + g) * 8;
    float s1 = 0.f, s2 = 0.f;
    #pragma unroll
    for (int p = 0; p < 8; ++p) { s1 += pp[p].x; s2 += pp[p].y; }
    float mu = s1 / 100352.f;
    float var = s2 / 100352.f - mu * mu;
    float rs = rsqrtf(var + 1e-5f);

    float ga[4], be[4];
    #pragma unroll
    for (int i = 0; i < 4; ++i) { ga[i] = gamma[4 * c4 + i]; be[i] = beta[4 * c4 + i]; }

    int rkey = c4 & 7;                   // read-side XOR key
    for (int j = wb; j < 14; j += 4) {
        float4 v[4];
        #pragma unroll
        for (int i = 0; i < 4; ++i)
            v[i] = xs[(4 * c4 + i) * 16 + (j ^ rkey)];
        int qv[4][4];
        #pragma unroll
        for (int i = 0; i < 4; ++i) {
            float f[4] = {v[i].x, v[i].y, v[i].z, v[i].w};
            #pragma unroll
            for (int s = 0; s < 4; ++s) {
                float yv = (f[s] - mu) * rs * ga[i] + be[i];
                float r  = fmaxf(yv, 0.f);
                float h2 = fminf(r * r, a_c);
                qv[i][s] = (int)rintf(h2 * S) - 128;
            }
        }
        #pragma unroll
        for (int s = 0; s < 4; ++s) {
            int packed = (qv[0][s] & 255) | ((qv[1][s] & 255) << 8) |
                         ((qv[2][s] & 255) << 16) | (qv[3][s] << 24);
            *(int*)(qrow + (j * 4 + s + 1) * C_ + 4 * c4) = packed;
        }
    }
}

// ---------------------------------------------------------------------------
// Kernel 3 (v8 = r7 winner + T5 setprio): implicit-GEMM conv, i8 MFMA.
// 256 thr / 128x128 tile, 32KB LDS, ~60V+64A regs -> FOUR independent
// barrier domains per CU (the proven structure: 72.4us, MfmaUtil 32%).
// NEW: s_setprio(1) around each 16-MFMA cluster. Mechanism (m191): with 4
// blocks at staggered phases on one CU, setprio lets MFMA-phase waves win
// issue arbitration over staging-phase waves. SALU-only -- cannot perturb
// the VGPR-60/4-block resource profile. Grid 1568 = 8*196 XCD-chunked.
// Exact integer arithmetic; epilogue adds 128*tsum[oc] shift correction.
// ---------------------------------------------------------------------------
__global__ __launch_bounds__(256, 4)
void conv_gemm_kernel(const char* __restrict__ q, const char* __restrict__ wt,
                      const float* __restrict__ alphas, const float* __restrict__ bias,
                      const float* __restrict__ tsum, const float* __restrict__ a_ptr,
                      float* __restrict__ out) {
    int bid = blockIdx.x;                     // 1568 = 8 * 196
    int virt = (bid & 7) * 196 + (bid >> 3);  // XCD-chunked bijective swizzle
    int mt = virt >> 1;                       // 784 M-tiles of 128
    int nh = virt & 1;                        // N-half (oc base = nh*128)
    int tid = threadIdx.x;                    // 0..255
    int lane = tid & 63;
    int wv = tid >> 6;                        // 0..3
    int wm = wv & 1, wn = wv >> 1;            // 2x2 waves of 64x64
    int quad = lane >> 4, lrow = lane & 15;

    __shared__ char As[128 * 128];   // 16 KB
    __shared__ char Bs[128 * 128];   // 16 KB

    // XOR bank swizzle on 16B K-blocks: slot kb holds global kb ^ (row&7)
    int kswz = (((tid & 7) ^ ((tid >> 3) & 7)) << 4);
    int sb[4], wb[4];
    #pragma unroll
    for (int r = 0; r < 4; ++r) {            // A rows: r*32 + (tid>>3)
        int ml = r * 32 + (tid >> 3);
        int m = mt * 128 + ml;
        int b = m / HW_;
        int rem = m - b * HW_;
        int hh = rem / W_;
        int ww = rem - hh * W_;
        sb[r] = ((b * P_ + hh + 1) * P_ + (ww + 1)) * C_ + kswz;
    }
    #pragma unroll
    for (int r = 0; r < 4; ++r) {            // B rows: local oc r*32 + (tid>>3)
        int oc = nh * 128 + r * 32 + (tid >> 3);
        wb[r] = oc * C_ + kswz;
    }

    i32x4 acc[4][4];
    #pragma unroll
    for (int i = 0; i < 4; ++i)
        #pragma unroll
        for (int j = 0; j < 4; ++j) { acc[i][j][0]=0; acc[i][j][1]=0; acc[i][j][2]=0; acc[i][j][3]=0; }

    int arow = wm * 64 + lrow;
    int brow = wn * 64 + lrow;
    int rsw = lrow & 7;          // read-side XOR key

    for (int kk = 0; kk < 18; ++kk) {
        int tap = kk >> 1;
        int ic0 = (kk & 1) << 7;
        int dh = tap / 3 - 1;
        int dw = tap - (tap / 3) * 3 - 1;
        int aoff = (dh * P_ + dw) * C_ + ic0;
        const char* gb = wt + (size_t)tap * (256 * 256) + ic0;
        #pragma unroll
        for (int r = 0; r < 4; ++r) {
            __builtin_amdgcn_global_load_lds(
                (const __attribute__((address_space(1))) void*)(q + sb[r] + aoff),
                (__attribute__((address_space(3))) void*)(&As[r * 4096 + tid * 16]),
                16, 0, 0);
        }
        #pragma unroll
        for (int r = 0; r < 4; ++r) {
            __builtin_amdgcn_global_load_lds(
                (const __attribute__((address_space(1))) void*)(gb + wb[r]),
                (__attribute__((address_space(3))) void*)(&Bs[r * 4096 + tid * 16]),
                16, 0, 0);
        }
        __syncthreads();
        #pragma unroll
        for (int ks = 0; ks < 2; ++ks) {
            int cb = (ks * 4 + quad) ^ rsw;
            i32x4 af[4], bf[4];
            #pragma unroll
            for (int mi = 0; mi < 4; ++mi)
                af[mi] = *(const i32x4*)&As[(arow + mi * 16) * 128 + cb * 16];
            #pragma unroll
            for (int ni = 0; ni < 4; ++ni)
                bf[ni] = *(const i32x4*)&Bs[(brow + ni * 16) * 128 + cb * 16];
            __builtin_amdgcn_s_setprio(1);
            #pragma unroll
            for (int mi = 0; mi < 4; ++mi)
                #pragma unroll
                for (int ni = 0; ni < 4; ++ni)
                    acc[mi][ni] = __builtin_amdgcn_mfma_i32_16x16x64_i8(
                        af[mi], bf[ni], acc[mi][ni], 0, 0, 0);
            __builtin_amdgcn_s_setprio(0);
        }
        __syncthreads();
    }

    float a_c = fmaxf(a_ptr[0], 0.f) + 1e-8f;
    float qs  = a_c * (1.f / 255.f);
    #pragma unroll
    for (int ni = 0; ni < 4; ++ni) {
        int n = nh * 128 + wn * 64 + ni * 16 + lrow;
        float sc = alphas[n] * qs;
        float bn = bias[n];
        float corr = 128.f * tsum[n];       // undo the -128 activation shift
        #pragma unroll
        for (int mi = 0; mi < 4; ++mi) {
            int mbase = mt * 128 + wm * 64 + mi * 16 + quad * 4;
            int b = mbase / HW_;
            size_t off = (size_t)b * (C_ * HW_) + (size_t)n * HW_ + (mbase - b * HW_);
            f32x4 v;
            #pragma unroll
            for (int r = 0; r < 4; ++r)
                v[r] = ((float)acc[mi][ni][r] + corr) * sc + bn;
            *(f32x4*)(out + off) = v;
        }
    }
}

// ---------------------------------------------------------------------------
extern "C" void kernel_launch(void* const* d_in, const int* in_sizes, int n_in,
                              void* d_out, int out_size, void* d_ws, size_t ws_size,
                              hipStream_t stream) {
    const float* x     = (const float*)d_in[0];
    const float* gamma = (const float*)d_in[1];
    const float* beta  = (const float*)d_in[2];
    const float* a     = (const float*)d_in[3];
    const float* wfp   = (const float*)d_in[4];
    const float* bias  = (const float*)d_in[5];
    float* out = (float*)d_out;

    char* ws = (char*)d_ws;
    char*   qbuf    = ws;                                      // 32*58*58*256 i8 = 27,557,888 B
    char*   wtb     = ws + 27557888;                           // 9*256*256 i8  = 589,824 B
    float*  alphas  = (float*)(ws + 27557888 + 589824);        // 256 fp32
    float*  tsum    = alphas + 256;                            // 256 fp32
    float2* partial = (float2*)(tsum + 256);                   // 2048 float2 = 16 KB

    prep_kernel<<<2304, 256, 0, stream>>>(x, wfp, partial, wtb, alphas, tsum);
    act_kernel<<<B_ * P_, 256, 0, stream>>>(x, gamma, beta, a, partial, qbuf);
    conv_gemm_kernel<<<1568, 256, 0, stream>>>(qbuf, wtb, alphas, bias, tsum, a, out);
}